// Round 2
// baseline (1335.810 us; speedup 1.0000x reference)
//
#include <hip/hip_runtime.h>

// Problem constants (from reference): z (64,128,64,64) f32, emb (256,128) f32
#define K_EMB   256
#define C_DIM   128
#define HW      4096            // 64*64
#define NPOS    262144          // 64*HW
#define Q_ELEMS 33554432        // 64*128*64*64
#define IDX_OFF Q_ELEMS         // idx chunk offset in d_out (floats)
#define LOSS_OFF (Q_ELEMS + NPOS)

#define TK 32                   // codes per k-chunk (accumulators per lane)
#define KHALF 128               // codes per thread-half (split-K factor 2)

// ws layout (floats): [0,256) enorm, [256] loss accumulator, [512, 512+32768) embT (c*256+k)
#define WS_ENORM 0
#define WS_ACC   256
#define WS_EMBT  512
#define WS_NEED_FULL  ((WS_EMBT + C_DIM * K_EMB) * 4)

// ---------------------------------------------------------------------------
// Kernel 0: per-code squared norms, emb transpose (c-major), zero loss accum.
// ---------------------------------------------------------------------------
__global__ __launch_bounds__(K_EMB) void vq_prep(const float* __restrict__ emb,
                                                 float* __restrict__ ws,
                                                 int use_embT) {
    int k = threadIdx.x;  // 256 threads, 1 block
    float s = 0.f;
    #pragma unroll 8
    for (int c = 0; c < C_DIM; ++c) {
        float e = emb[k * C_DIM + c];
        s = fmaf(e, e, s);
        if (use_embT) ws[WS_EMBT + c * K_EMB + k] = e;
    }
    ws[WS_ENORM + k] = s;
    if (k == 0) ws[WS_ACC] = 0.f;
}

// ---------------------------------------------------------------------------
// Kernel 1: split-K register-blocked VALU GEMM + argmin.
//
// R6 (this round): R5 counters -- VALUBusy 50%, HBM 20%, occupancy 38% --
// latency-bound with a STRUCTURAL wave cap: grid 1024 blocks / 256 CU = 16
// waves/CU max. Fix: split K across thread halves. 2048 blocks x 256 thr;
// block owns 128 positions; threads 0-127 score codes 0-127, threads
// 128-255 score codes 128-255 (TK=32, 4 chunks each). Combined regs ~60
// (acc parks in AGPRs; R0's TK=32 build measured 28 arch VGPRs) -> 8
// waves/EU feasible -> 32 waves/CU. The two halves read identical z lines
// -> L1/L2 line sharing eats the extra logical passes.
//
// Numerics: znorm is the same serial ascending-c fma chain (fused into each
// thread's first chunk); every dot is its own serial ascending-c chain;
// d = (znorm - 2*acc) + enorm[k]; within-half strict < ascending-k; combine
// prefers lo half unless best_hi < best_lo strictly (all lo k < all hi k =>
// global first-min preserved). Bit-identical distances and argmin to the
// R1/R5 kernels that passed with absmax 0.
// Loss: epilogue on lo half only -- same 128-term per-thread chain, same
// 64-consecutive-pos wave partition (4096 partials), same shfl tree, same
// atomic count as R5.
// ---------------------------------------------------------------------------
template <int UT, int ZN>
__device__ __forceinline__ void vq_chunk(const float* __restrict__ zp,
                                         const float* __restrict__ embT,
                                         const float* __restrict__ emb,
                                         int kc, float* __restrict__ acc,
                                         float& znorm) {
    #pragma unroll
    for (int j = 0; j < TK; ++j) acc[j] = 0.f;

    #pragma unroll 2
    for (int c = 0; c < C_DIM; ++c) {
        float zc = zp[(size_t)c * HW];            // per-lane vector load
        if (ZN) znorm = fmaf(zc, zc, znorm);      // same serial chain as before
        if (UT) {
            const float* __restrict__ ep = embT + c * K_EMB + kc;  // wave-uniform
            #pragma unroll
            for (int j = 0; j < TK; ++j)
                acc[j] = fmaf(zc, ep[j], acc[j]); // VGPR x SGPR fmac
        } else {
            #pragma unroll
            for (int j = 0; j < TK; ++j)
                acc[j] = fmaf(zc, emb[(kc + j) * C_DIM + c], acc[j]);
        }
    }
}

template <int UT>
__global__ __launch_bounds__(256, 6) void vq_main(const float* __restrict__ z,
                                                  const float* __restrict__ emb,
                                                  const float* __restrict__ ws,
                                                  float* __restrict__ out,
                                                  float* __restrict__ loss_acc) {
    const int t    = threadIdx.x;
    const int p    = t & (KHALF - 1);                 // position within block
    const int half = t >> 7;                          // 0: k 0-127, 1: k 128-255
    const int pos  = blockIdx.x * KHALF + p;          // flat (b, h, w)
    const int b    = pos >> 12;                       // / 4096
    const int hw   = pos & 4095;

    const float* __restrict__ zp    = z + (size_t)b * (C_DIM * HW) + hw;
    const float* __restrict__ embT  = ws + WS_EMBT;
    const float* __restrict__ enorm = ws + WS_ENORM;

    float znorm = 0.f;
    float best  = 3.402823466e38f;
    int   bidx  = 0;
    float acc[TK];

    const int kbase = half * KHALF;

    // first chunk: znorm fused into the same z stream.
    vq_chunk<UT, 1>(zp, embT, emb, kbase, acc, znorm);
    #pragma unroll
    for (int j = 0; j < TK; ++j) {
        float d = (znorm - 2.0f * acc[j]) + enorm[kbase + j];
        if (d < best) { best = d; bidx = kbase + j; }   // strict < = first-min
    }

    for (int kc = kbase + TK; kc < kbase + KHALF; kc += TK) {
        vq_chunk<UT, 0>(zp, embT, emb, kc, acc, znorm);
        #pragma unroll
        for (int j = 0; j < TK; ++j) {
            float d = (znorm - 2.0f * acc[j]) + enorm[kc + j];
            if (d < best) { best = d; bidx = kc + j; }
        }
    }

    // Combine the two half-argmins per position through LDS.
    __shared__ float sh_best[256];
    __shared__ int   sh_bidx[256];
    sh_best[t] = best;
    sh_bidx[t] = bidx;
    __syncthreads();

    const float blo = sh_best[p];
    const int   ilo = sh_bidx[p];
    const float bhi = sh_best[KHALF + p];
    const int   ihi = sh_bidx[KHALF + p];
    const int   fin = (bhi < blo) ? ihi : ilo;        // lo wins ties (lower k)

    if (half == 0) {
        __builtin_nontemporal_store((float)fin, &out[IDX_OFF + pos]);

        // Epilogue: quantized_ste = z + (e - z), accumulate (e - z)^2.
        // Same 128-term chain / wave partition / atomic count as the passing
        // R5 kernel. z re-read is L2/L3-hot; q write is NT so the 134 MB
        // write stream doesn't evict z from L3.
        float lsum = 0.f;
        float* qp = out + (size_t)b * (C_DIM * HW) + hw;
        #pragma unroll 4
        for (int c = 0; c < C_DIM; ++c) {
            float zc = zp[(size_t)c * HW];
            float e  = UT ? embT[c * K_EMB + fin] : emb[fin * C_DIM + c];
            float dq = e - zc;
            lsum = fmaf(dq, dq, lsum);
            __builtin_nontemporal_store(zc + dq, &qp[(size_t)c * HW]);
        }

        // Wave-level reduction, one atomic per (lo) wave.
        #pragma unroll
        for (int off = 32; off > 0; off >>= 1)
            lsum += __shfl_down(lsum, off, 64);
        if ((t & 63) == 0) atomicAdd(loss_acc, lsum);
    }
}

// ---------------------------------------------------------------------------
// Kernel 2: finalize the two scalar losses.
// ---------------------------------------------------------------------------
__global__ void vq_finalize(const float* __restrict__ loss_acc,
                            float* __restrict__ out_losses) {
    float S = loss_acc[0];
    float mean = S / (float)Q_ELEMS;
    out_losses[0] = 0.25f * mean;  // commitment_loss
    out_losses[1] = mean;          // codebook_loss
}

extern "C" void kernel_launch(void* const* d_in, const int* in_sizes, int n_in,
                              void* d_out, int out_size, void* d_ws, size_t ws_size,
                              hipStream_t stream) {
    const float* z   = (const float*)d_in[0];
    const float* emb = (const float*)d_in[1];
    float* out = (float*)d_out;
    float* ws  = (float*)d_ws;

    int use_embT = (ws_size >= (size_t)WS_NEED_FULL) ? 1 : 0;

    vq_prep<<<1, K_EMB, 0, stream>>>(emb, ws, use_embT);
    if (use_embT)
        vq_main<1><<<NPOS / KHALF, 256, 0, stream>>>(z, emb, ws, out, ws + WS_ACC);
    else
        vq_main<0><<<NPOS / KHALF, 256, 0, stream>>>(z, emb, ws, out, ws + WS_ACC);
    vq_finalize<<<1, 1, 0, stream>>>(ws + WS_ACC, out + LOSS_OFF);
}

// Round 3
// 501.055 us; speedup vs baseline: 2.6660x; 2.6660x over previous
//
#include <hip/hip_runtime.h>

// Problem constants (from reference): z (64,128,64,64) f32, emb (256,128) f32
#define K_EMB   256
#define C_DIM   128
#define HW      4096            // 64*64
#define NPOS    262144          // 64*HW
#define Q_ELEMS 33554432        // 64*128*64*64
#define IDX_OFF Q_ELEMS         // idx chunk offset in d_out (floats)
#define LOSS_OFF (Q_ELEMS + NPOS)

#define TK 32                   // codes per k-chunk (accumulators per lane)
#define KHALF 128               // codes per thread-half (split-K factor 2)

// ws layout (floats): [0,256) enorm, [256] loss accumulator, [512, 512+32768) embT (c*256+k)
#define WS_ENORM 0
#define WS_ACC   256
#define WS_EMBT  512
#define WS_NEED_FULL  ((WS_EMBT + C_DIM * K_EMB) * 4)

// ---------------------------------------------------------------------------
// Kernel 0: per-code squared norms, emb transpose (c-major), zero loss accum.
// ---------------------------------------------------------------------------
__global__ __launch_bounds__(K_EMB) void vq_prep(const float* __restrict__ emb,
                                                 float* __restrict__ ws,
                                                 int use_embT) {
    int k = threadIdx.x;  // 256 threads, 1 block
    float s = 0.f;
    #pragma unroll 8
    for (int c = 0; c < C_DIM; ++c) {
        float e = emb[k * C_DIM + c];
        s = fmaf(e, e, s);
        if (use_embT) ws[WS_EMBT + c * K_EMB + k] = e;
    }
    ws[WS_ENORM + k] = s;
    if (k == 0) ws[WS_ACC] = 0.f;
}

// ---------------------------------------------------------------------------
// Kernel 1: split-K register-blocked VALU GEMM + argmin.
//
// R7 (this round): R6's split-K regressed 292 -> 1206 us. Diagnosis from
// counters: VALUBusy 19%, HBM 5%, FETCH unchanged -- the inner-loop embT
// address became divergent in the compiler's eyes because kbase derived
// from threadIdx.x>>7. R5's premise (wave-uniform address -> SCALAR loads,
// one s_load_dwordx16 feeding 32 v_fmac) silently degraded to 32 per-lane
// VECTOR loads per c-step -> VMEM-issue-bound. kbase IS uniform across
// each 64-lane wave by construction (half flips at t=128), so launder it
// through readfirstlane to pin it in an SGPR and restore scalar codegen.
//
// Numerics unchanged from the absmax-0 R5/R6 kernels: znorm same serial
// ascending-c fma chain (fused in first chunk); each dot its own serial
// chain; d = (znorm - 2*acc) + enorm[k]; within-half strict < ascending-k;
// combine prefers lo half unless strictly better (all lo k < all hi k =>
// global first-min preserved). readfirstlane of a wave-uniform value is a
// pure addressing transform. Loss epilogue identical to R5 (same 128-term
// chains, same 4096-wave partition, same atomic count).
// ---------------------------------------------------------------------------
template <int UT, int ZN>
__device__ __forceinline__ void vq_chunk(const float* __restrict__ zp,
                                         const float* __restrict__ embT,
                                         const float* __restrict__ emb,
                                         int kc, float* __restrict__ acc,
                                         float& znorm) {
    #pragma unroll
    for (int j = 0; j < TK; ++j) acc[j] = 0.f;

    #pragma unroll 2
    for (int c = 0; c < C_DIM; ++c) {
        float zc = zp[(size_t)c * HW];            // per-lane vector load
        if (ZN) znorm = fmaf(zc, zc, znorm);      // same serial chain as before
        if (UT) {
            const float* __restrict__ ep = embT + c * K_EMB + kc;  // SGPR-uniform
            #pragma unroll
            for (int j = 0; j < TK; ++j)
                acc[j] = fmaf(zc, ep[j], acc[j]); // VGPR x SGPR fmac
        } else {
            #pragma unroll
            for (int j = 0; j < TK; ++j)
                acc[j] = fmaf(zc, emb[(kc + j) * C_DIM + c], acc[j]);
        }
    }
}

template <int UT>
__global__ __launch_bounds__(256, 6) void vq_main(const float* __restrict__ z,
                                                  const float* __restrict__ emb,
                                                  const float* __restrict__ ws,
                                                  float* __restrict__ out,
                                                  float* __restrict__ loss_acc) {
    const int t    = threadIdx.x;
    const int p    = t & (KHALF - 1);                 // position within block
    const int half = t >> 7;                          // 0: k 0-127, 1: k 128-255
    const int pos  = blockIdx.x * KHALF + p;          // flat (b, h, w)
    const int b    = pos >> 12;                       // / 4096
    const int hw   = pos & 4095;

    const float* __restrict__ zp    = z + (size_t)b * (C_DIM * HW) + hw;
    const float* __restrict__ embT  = ws + WS_EMBT;
    const float* __restrict__ enorm = ws + WS_ENORM;

    float znorm = 0.f;
    float best  = 3.402823466e38f;
    int   bidx  = 0;
    float acc[TK];

    // half is uniform across each 64-lane wave (flips at t=128): pin the
    // k-base in an SGPR so embT/enorm indexing compiles to SCALAR loads.
    const int kbase = __builtin_amdgcn_readfirstlane(half * KHALF);

    // first chunk: znorm fused into the same z stream.
    vq_chunk<UT, 1>(zp, embT, emb, kbase, acc, znorm);
    #pragma unroll
    for (int j = 0; j < TK; ++j) {
        float d = (znorm - 2.0f * acc[j]) + enorm[kbase + j];
        if (d < best) { best = d; bidx = kbase + j; }   // strict < = first-min
    }

    for (int kc = kbase + TK; kc < kbase + KHALF; kc += TK) {
        vq_chunk<UT, 0>(zp, embT, emb, kc, acc, znorm);
        #pragma unroll
        for (int j = 0; j < TK; ++j) {
            float d = (znorm - 2.0f * acc[j]) + enorm[kc + j];
            if (d < best) { best = d; bidx = kc + j; }
        }
    }

    // Combine the two half-argmins per position through LDS.
    __shared__ float sh_best[256];
    __shared__ int   sh_bidx[256];
    sh_best[t] = best;
    sh_bidx[t] = bidx;
    __syncthreads();

    const float blo = sh_best[p];
    const int   ilo = sh_bidx[p];
    const float bhi = sh_best[KHALF + p];
    const int   ihi = sh_bidx[KHALF + p];
    const int   fin = (bhi < blo) ? ihi : ilo;        // lo wins ties (lower k)

    if (half == 0) {
        __builtin_nontemporal_store((float)fin, &out[IDX_OFF + pos]);

        // Epilogue: quantized_ste = z + (e - z), accumulate (e - z)^2.
        // Same 128-term chain / wave partition / atomic count as the passing
        // R5 kernel. z re-read is L2/L3-hot; q write is NT so the 134 MB
        // write stream doesn't evict z from L3.
        float lsum = 0.f;
        float* qp = out + (size_t)b * (C_DIM * HW) + hw;
        #pragma unroll 4
        for (int c = 0; c < C_DIM; ++c) {
            float zc = zp[(size_t)c * HW];
            float e  = UT ? embT[c * K_EMB + fin] : emb[fin * C_DIM + c];
            float dq = e - zc;
            lsum = fmaf(dq, dq, lsum);
            __builtin_nontemporal_store(zc + dq, &qp[(size_t)c * HW]);
        }

        // Wave-level reduction, one atomic per (lo) wave.
        #pragma unroll
        for (int off = 32; off > 0; off >>= 1)
            lsum += __shfl_down(lsum, off, 64);
        if ((t & 63) == 0) atomicAdd(loss_acc, lsum);
    }
}

// ---------------------------------------------------------------------------
// Kernel 2: finalize the two scalar losses.
// ---------------------------------------------------------------------------
__global__ void vq_finalize(const float* __restrict__ loss_acc,
                            float* __restrict__ out_losses) {
    float S = loss_acc[0];
    float mean = S / (float)Q_ELEMS;
    out_losses[0] = 0.25f * mean;  // commitment_loss
    out_losses[1] = mean;          // codebook_loss
}

extern "C" void kernel_launch(void* const* d_in, const int* in_sizes, int n_in,
                              void* d_out, int out_size, void* d_ws, size_t ws_size,
                              hipStream_t stream) {
    const float* z   = (const float*)d_in[0];
    const float* emb = (const float*)d_in[1];
    float* out = (float*)d_out;
    float* ws  = (float*)d_ws;

    int use_embT = (ws_size >= (size_t)WS_NEED_FULL) ? 1 : 0;

    vq_prep<<<1, K_EMB, 0, stream>>>(emb, ws, use_embT);
    if (use_embT)
        vq_main<1><<<NPOS / KHALF, 256, 0, stream>>>(z, emb, ws, out, ws + WS_ACC);
    else
        vq_main<0><<<NPOS / KHALF, 256, 0, stream>>>(z, emb, ws, out, ws + WS_ACC);
    vq_finalize<<<1, 1, 0, stream>>>(ws + WS_ACC, out + LOSS_OFF);
}

// Round 4
// 400.425 us; speedup vs baseline: 3.3360x; 1.2513x over previous
//
#include <hip/hip_runtime.h>

// Problem constants (from reference): z (64,128,64,64) f32, emb (256,128) f32
#define K_EMB   256
#define C_DIM   128
#define HW      4096            // 64*64
#define NPOS    262144          // 64*HW
#define Q_ELEMS 33554432        // 64*128*64*64
#define IDX_OFF Q_ELEMS         // idx chunk offset in d_out (floats)
#define LOSS_OFF (Q_ELEMS + NPOS)

#define BLKP 64                 // positions per block (z tile = 128c x 64p = 32 KB LDS)
#define TK   64                 // codes per thread (one chunk, acc in unified VGPR/AGPR)
#define NQ   4                  // k-quarters = waves per block

// ws layout (floats): [0,256) enorm, [256] loss accumulator, [512, 512+32768) embT (c*256+k)
#define WS_ENORM 0
#define WS_ACC   256
#define WS_EMBT  512
#define WS_NEED_FULL  ((WS_EMBT + C_DIM * K_EMB) * 4)

// ---------------------------------------------------------------------------
// Kernel A: parallel emb transpose (one block per c), zero loss accum.
// (prep runs every iteration; the old 1-block gather version serialized
//  8192 uncoalesced line fetches on a single CU)
// ---------------------------------------------------------------------------
__global__ __launch_bounds__(K_EMB) void vq_transpose(const float* __restrict__ emb,
                                                      float* __restrict__ ws,
                                                      int use_embT) {
    const int c = blockIdx.x, k = threadIdx.x;
    if (use_embT) ws[WS_EMBT + c * K_EMB + k] = emb[k * C_DIM + c];
    if (c == 0 && k == 0) ws[WS_ACC] = 0.f;
}

// ---------------------------------------------------------------------------
// Kernel B: per-code squared norms. Same ascending-c serial fmaf chain as the
// absmax-0 kernels (float4 components consumed in x,y,z,w = ascending c).
// ---------------------------------------------------------------------------
__global__ __launch_bounds__(K_EMB) void vq_enorm(const float* __restrict__ emb,
                                                  float* __restrict__ ws) {
    const int k = threadIdx.x;
    const float4* __restrict__ er = reinterpret_cast<const float4*>(emb + k * C_DIM);
    float s = 0.f;
    #pragma unroll
    for (int j = 0; j < C_DIM / 4; ++j) {
        float4 v = er[j];
        s = fmaf(v.x, v.x, s);
        s = fmaf(v.y, v.y, s);
        s = fmaf(v.z, v.z, s);
        s = fmaf(v.w, v.w, s);
    }
    ws[WS_ENORM + k] = s;
}

// ---------------------------------------------------------------------------
// Kernel 1: LDS-staged split-K VALU GEMM + argmin.
//
// R8 (this round): R7 counters -- VALUBusy 45%, occupancy 55%, FETCH 317 MB
// -- per-wave VALU duty ~10%: every wave stalls ~600 cyc on the global z
// re-stream (z still read 2.4x from L3/HBM). More waves of the same shape
// can't fix a shared long-latency stream, so remove it: stage the block's z
// tile (128c x 64p = 32 KB) in LDS ONCE, then the dot loop reads z via
// conflict-free ds_read_b32 (lanes = consecutive p). Global z traffic drops
// 5 passes -> 1. Block = 4 waves = 4 k-quarters, TK=64, kbase laundered
// through readfirstlane (R7-proven) so embT stays on the SCALAR pipe
// (s_load_dwordx16 feeding v_fmac VGPRxSGPR).
//
// Numerics: bit-identical to the absmax-0 lineage. znorm = same serial
// ascending-c fmaf chain (computed redundantly per quarter, same bits);
// each dot its own serial ascending-c chain; d = (znorm - 2*acc) +
// enorm[k]; strict < ascending-k within a quarter, ascending-quarter
// strict < combine = global first-min. LDS z is a bit-copy. Loss epilogue:
// same 64-consecutive-position wave partition (4096 partials), same
// 128-term per-thread ascending-c chains, same shfl tree, same atomic
// count. e fetched from row-major emb (bit-equal to embT).
// ---------------------------------------------------------------------------
template <int UT>
__global__ __launch_bounds__(256, 4) void vq_main(const float* __restrict__ z,
                                                  const float* __restrict__ emb,
                                                  const float* __restrict__ ws,
                                                  float* __restrict__ out,
                                                  float* __restrict__ loss_acc) {
    __shared__ float zlds[C_DIM * BLKP];   // [c][p], 32 KB
    __shared__ float sh_best[256];
    __shared__ int   sh_bidx[256];

    const int t   = threadIdx.x;
    const int p   = t & (BLKP - 1);            // position within block
    const int kq  = t >> 6;                    // wave id = k-quarter
    const int blk = blockIdx.x;
    const int b   = blk >> 6;                  // 4096/64 blocks per image
    const int hw0 = (blk & 63) * BLKP;
    const size_t zoff = (size_t)b * (C_DIM * HW) + hw0;
    const float* __restrict__ zsrc = z + zoff;

    // ---- Stage z tile into LDS (coalesced float4; [c][p] layout) ----
    {
        const float4* __restrict__ zs4 = reinterpret_cast<const float4*>(zsrc);
        float4* __restrict__ zl4 = reinterpret_cast<float4*>(zlds);
        #pragma unroll
        for (int j = 0; j < (C_DIM * BLKP / 4) / 256; ++j) {   // 8 iters
            const int i4 = t + j * 256;
            const int c  = i4 >> 4;            // 16 float4 per c-row
            const int p4 = i4 & 15;
            zl4[i4] = zs4[(size_t)c * (HW / 4) + p4];
        }
    }
    __syncthreads();

    const float* __restrict__ embT  = ws + WS_EMBT;
    const float* __restrict__ enorm = ws + WS_ENORM;

    // kq is uniform across each 64-lane wave: pin k-base in an SGPR so
    // embT/enorm indexing compiles to SCALAR loads (R6 lesson, R7 fix).
    const int kbase = __builtin_amdgcn_readfirstlane(kq * TK);

    float acc[TK];
    #pragma unroll
    for (int j = 0; j < TK; ++j) acc[j] = 0.f;
    float znorm = 0.f;

    #pragma unroll 2
    for (int c = 0; c < C_DIM; ++c) {
        const float zc = zlds[c * BLKP + p];   // conflict-free ds_read_b32
        znorm = fmaf(zc, zc, znorm);           // same serial chain as before
        if (UT) {
            const float* __restrict__ ep = embT + c * K_EMB + kbase;  // SGPR-uniform
            #pragma unroll
            for (int j = 0; j < TK; ++j)
                acc[j] = fmaf(zc, ep[j], acc[j]);   // v_fmac VGPR x SGPR
        } else {
            #pragma unroll
            for (int j = 0; j < TK; ++j)
                acc[j] = fmaf(zc, emb[(kbase + j) * C_DIM + c], acc[j]);
        }
    }

    float best = 3.402823466e38f;
    int   bidx = 0;
    #pragma unroll
    for (int j = 0; j < TK; ++j) {
        const float d = (znorm - 2.0f * acc[j]) + enorm[kbase + j];
        if (d < best) { best = d; bidx = kbase + j; }   // strict < = first-min
    }

    sh_best[t] = best;
    sh_bidx[t] = bidx;
    __syncthreads();

    if (kq == 0) {   // wave 0 finishes its 64 positions
        float bb = sh_best[p];
        int   bi = sh_bidx[p];
        #pragma unroll
        for (int q = 1; q < NQ; ++q) {
            const float bq = sh_best[q * BLKP + p];
            const int   iq = sh_bidx[q * BLKP + p];
            if (bq < bb) { bb = bq; bi = iq; }  // strict <: lower quarter wins ties
        }
        const int fin = bi;
        const int pos = blk * BLKP + p;
        __builtin_nontemporal_store((float)fin, &out[IDX_OFF + pos]);

        // Epilogue: q = z + (e - z), loss += (e - z)^2. z from LDS (bit-copy),
        // e from row-major emb via float4 (bit-equal to embT), ascending-c
        // 128-term chain identical to the absmax-0 lineage.
        float lsum = 0.f;
        float* qp = out + zoff + p;
        const float4* __restrict__ er =
            reinterpret_cast<const float4*>(emb + fin * C_DIM);
        #pragma unroll 4
        for (int j = 0; j < C_DIM / 4; ++j) {
            const float4 ev = er[j];
            const int c0 = j * 4;
            const float z0 = zlds[(c0 + 0) * BLKP + p];
            const float z1 = zlds[(c0 + 1) * BLKP + p];
            const float z2 = zlds[(c0 + 2) * BLKP + p];
            const float z3 = zlds[(c0 + 3) * BLKP + p];
            const float d0 = ev.x - z0, d1 = ev.y - z1;
            const float d2 = ev.z - z2, d3 = ev.w - z3;
            lsum = fmaf(d0, d0, lsum);
            lsum = fmaf(d1, d1, lsum);
            lsum = fmaf(d2, d2, lsum);
            lsum = fmaf(d3, d3, lsum);
            __builtin_nontemporal_store(z0 + d0, &qp[(size_t)(c0 + 0) * HW]);
            __builtin_nontemporal_store(z1 + d1, &qp[(size_t)(c0 + 1) * HW]);
            __builtin_nontemporal_store(z2 + d2, &qp[(size_t)(c0 + 2) * HW]);
            __builtin_nontemporal_store(z3 + d3, &qp[(size_t)(c0 + 3) * HW]);
        }

        // Wave-level reduction, one atomic per block (same 4096 partials).
        #pragma unroll
        for (int off = 32; off > 0; off >>= 1)
            lsum += __shfl_down(lsum, off, 64);
        if (p == 0) atomicAdd(loss_acc, lsum);
    }
}

// ---------------------------------------------------------------------------
// Kernel 2: finalize the two scalar losses.
// ---------------------------------------------------------------------------
__global__ void vq_finalize(const float* __restrict__ loss_acc,
                            float* __restrict__ out_losses) {
    float S = loss_acc[0];
    float mean = S / (float)Q_ELEMS;
    out_losses[0] = 0.25f * mean;  // commitment_loss
    out_losses[1] = mean;          // codebook_loss
}

extern "C" void kernel_launch(void* const* d_in, const int* in_sizes, int n_in,
                              void* d_out, int out_size, void* d_ws, size_t ws_size,
                              hipStream_t stream) {
    const float* z   = (const float*)d_in[0];
    const float* emb = (const float*)d_in[1];
    float* out = (float*)d_out;
    float* ws  = (float*)d_ws;

    int use_embT = (ws_size >= (size_t)WS_NEED_FULL) ? 1 : 0;

    vq_transpose<<<C_DIM, K_EMB, 0, stream>>>(emb, ws, use_embT);
    vq_enorm<<<1, K_EMB, 0, stream>>>(emb, ws);
    if (use_embT)
        vq_main<1><<<NPOS / BLKP, 256, 0, stream>>>(z, emb, ws, out, ws + WS_ACC);
    else
        vq_main<0><<<NPOS / BLKP, 256, 0, stream>>>(z, emb, ws, out, ws + WS_ACC);
    vq_finalize<<<1, 1, 0, stream>>>(ws + WS_ACC, out + LOSS_OFF);
}